// Round 23
// baseline (378.663 us; speedup 1.0000x reference)
//
#include <hip/hip_runtime.h>

#define NN 100000
#define NE 1200000
#define NG 8
#define DIM 64
#define SCAN_BS 256
#define NB ((NN + SCAN_BS - 1) / SCAN_BS)  // 391
#define COLCAP (NE + 7 * NN)  // ceil8 padding worst case

// histogram partition: 7 ranges x 16384 nodes (64KB LDS), 28 edge slices
#define RANGE 16384
#define RSH 14
#define NR 7
#define GSL 28
#define SLICE4 ((NE / 4 + GSL - 1) / GSL)  // 10715

__device__ __forceinline__ unsigned bf16rne(float f) {
  unsigned u = __float_as_uint(f);
  return (u + 0x7FFF + ((u >> 16) & 1)) >> 16;
}
__device__ __forceinline__ float bflo(unsigned u) { return __uint_as_float(u << 16); }
__device__ __forceinline__ float bfhi(unsigned u) { return __uint_as_float(u & 0xFFFF0000u); }

// ---- range-partitioned LDS histogram ----
__global__ __launch_bounds__(256) void hist_kernel(const int4* __restrict__ esrc4,
                                                   const int4* __restrict__ edst4,
                                                   int* __restrict__ partial) {
  __shared__ int h[RANGE];
  int job = blockIdx.x;
  int g = job % GSL;
  int r = (job / GSL) % NR;
  int dir = job / (GSL * NR);
  const int4* __restrict__ idx = dir ? edst4 : esrc4;
  int lo = r * RANGE, hi = min(lo + RANGE, NN);
  for (int i = threadIdx.x; i < RANGE / 4; i += 256) ((int4*)h)[i] = make_int4(0, 0, 0, 0);
  __syncthreads();
  int s0 = g * SLICE4, s1 = min(s0 + SLICE4, NE / 4);
  for (int i = s0 + threadIdx.x; i < s1; i += 256) {
    int4 v = idx[i];
    if (v.x >= lo && v.x < hi) atomicAdd(&h[v.x - lo], 1);
    if (v.y >= lo && v.y < hi) atomicAdd(&h[v.y - lo], 1);
    if (v.z >= lo && v.z < hi) atomicAdd(&h[v.z - lo], 1);
    if (v.w >= lo && v.w < hi) atomicAdd(&h[v.w - lo], 1);
  }
  __syncthreads();
  int4* dst = (int4*)(partial + (size_t)job * RANGE);
  int cap4 = (hi - lo) >> 2;
  for (int i = threadIdx.x; i < cap4; i += 256) dst[i] = ((int4*)h)[i];
}

// ---- fused reduce + scan1 ----
__global__ __launch_bounds__(SCAN_BS) void scan1_kernel(const int* __restrict__ partial,
                                                        float* __restrict__ snormA,
                                                        float* __restrict__ dnormA,
                                                        int* __restrict__ rp2,
                                                        int* __restrict__ bsum, int N) {
  __shared__ int t[SCAN_BS];
  int i = blockIdx.x * SCAN_BS + threadIdx.x;
  int v = 0;
  if (i < N) {
    int r = i >> RSH, off = i & (RANGE - 1);
    const int* ps = partial + ((size_t)r * GSL) * RANGE + off;
    const int* pd = partial + (((size_t)NR + r) * GSL) * RANGE + off;
    int sOut = 0, sIn = 0;
#pragma unroll
    for (int g = 0; g < GSL; ++g) {
      sOut += ps[(size_t)g * RANGE];
      sIn += pd[(size_t)g * RANGE];
    }
    snormA[i] = rsqrtf(fmaxf((float)sOut, 1.0f));
    dnormA[i] = rsqrtf(fmaxf((float)sIn, 1.0f));
    v = (sIn + 7) & ~7;
  }
  t[threadIdx.x] = v;
  __syncthreads();
  for (int off = 1; off < SCAN_BS; off <<= 1) {
    int u = (threadIdx.x >= off) ? t[threadIdx.x - off] : 0;
    __syncthreads();
    t[threadIdx.x] += u;
    __syncthreads();
  }
  if (i < N) rp2[i] = t[threadIdx.x] - v;
  if (i == N - 1) rp2[N] = t[threadIdx.x];
  if (threadIdx.x == SCAN_BS - 1) bsum[blockIdx.x] = t[threadIdx.x];
}

__global__ __launch_bounds__(512) void scan2_kernel(const int* __restrict__ bsum,
                                                    int* __restrict__ boff, int nb) {
  __shared__ int t[512];
  int v = ((int)threadIdx.x < nb) ? bsum[threadIdx.x] : 0;
  t[threadIdx.x] = v;
  __syncthreads();
  for (int off = 1; off < 512; off <<= 1) {
    int u = (threadIdx.x >= off) ? t[threadIdx.x - off] : 0;
    __syncthreads();
    t[threadIdx.x] += u;
    __syncthreads();
  }
  boff[threadIdx.x] = t[threadIdx.x] - v;
}

__global__ __launch_bounds__(SCAN_BS) void scan3_kernel(int* __restrict__ rp2,
                                                        const int* __restrict__ boff, int N) {
  int i = blockIdx.x * SCAN_BS + threadIdx.x;
  if (i < N) rp2[i] += boff[blockIdx.x];
  if (i == N - 1) rp2[N] += boff[blockIdx.x];
}

// ---- in-place: partial[1][r][g][i] -> absolute start offset ----
__global__ void offscan_kernel(int* __restrict__ partial, const int* __restrict__ rp2, int N) {
  int n = blockIdx.x * blockDim.x + threadIdx.x;
  if (n >= N) return;
  int r = n >> RSH, i = n & (RANGE - 1);
  int* p = partial + (((size_t)NR + r) * GSL) * RANGE + i;
  int running = rp2[n];
#pragma unroll
  for (int g = 0; g < GSL; ++g) {
    int tmp = p[(size_t)g * RANGE];
    p[(size_t)g * RANGE] = running;
    running += tmp;
  }
}

// ---- init col with NN (zero-row index) ----
__global__ void colinit_kernel(int4* __restrict__ col4, int n4) {
  int i = blockIdx.x * blockDim.x + threadIdx.x;
  int st = gridDim.x * blockDim.x;
  for (; i < n4; i += st) col4[i] = make_int4(NN, NN, NN, NN);
}

// ---- fill CSR col ----
__global__ __launch_bounds__(256) void fill_kernel(const int4* __restrict__ esrc4,
                                                   const int4* __restrict__ edst4,
                                                   const int* __restrict__ partial,
                                                   int* __restrict__ col) {
  __shared__ int cnt[RANGE];
  int job = blockIdx.x;  // NR*GSL
  int g = job % GSL, r = job / GSL;
  int lo = r * RANGE, hi = min(lo + RANGE, NN);
  const int* off = partial + (((size_t)NR + r) * GSL + g) * RANGE;
  for (int i = threadIdx.x; i < hi - lo; i += 256) cnt[i] = off[i];
  __syncthreads();
  int s0 = g * SLICE4, s1 = min(s0 + SLICE4, NE / 4);
  for (int i = s0 + threadIdx.x; i < s1; i += 256) {
    int4 d = edst4[i];
    int4 s = esrc4[i];
    if (d.x >= lo && d.x < hi) col[atomicAdd(&cnt[d.x - lo], 1)] = s.x;
    if (d.y >= lo && d.y < hi) col[atomicAdd(&cnt[d.y - lo], 1)] = s.y;
    if (d.z >= lo && d.z < hi) col[atomicAdd(&cnt[d.z - lo], 1)] = s.z;
    if (d.w >= lo && d.w < hi) col[atomicAdd(&cnt[d.w - lo], 1)] = s.w;
  }
}

// ---- xb = bf16(features * snorm), RNE ----
__global__ void prescale_kernel(const float* __restrict__ f, const float* __restrict__ snormA,
                                unsigned short* __restrict__ xb, int N) {
  int i = blockIdx.x * blockDim.x + threadIdx.x;  // 8-elem chunk
  if (i < N * 8) {
    int n = i >> 3;
    float sn = snormA[n];
    const float4* p = (const float4*)(f + (size_t)i * 8);
    float4 a = p[0], b = p[1];
    uint4 o;
    o.x = bf16rne(a.x * sn) | (bf16rne(a.y * sn) << 16);
    o.y = bf16rne(a.z * sn) | (bf16rne(a.w * sn) << 16);
    o.z = bf16rne(b.x * sn) | (bf16rne(b.y * sn) << 16);
    o.w = bf16rne(b.z * sn) | (bf16rne(b.w * sn) << 16);
    ((uint4*)xb)[i] = o;
  }
}

// ---- fused gather(bf16) + dnorm + MLP(relu); 8 nodes/wave; low-LDS (no prefetch) ----
template <int POOL>
__global__ __launch_bounds__(256) void gconv_kernel(
    const unsigned short* __restrict__ xb, const float* __restrict__ snormA,
    const float* __restrict__ dnormA,
    const int* __restrict__ rp2, const int* __restrict__ col,
    const float* __restrict__ W, const float* __restrict__ b,
    unsigned short* __restrict__ outb, const int* __restrict__ gid,
    float* __restrict__ gsum, float* __restrict__ gcnt, int N) {
  __shared__ unsigned short Wtb[DIM * DIM];  // bf16 W, 8KB
  __shared__ float aL[4][8][DIM + 1];        // padded: write conflicts ~free
  __shared__ float lsum[POOL ? NG * DIM : 4];
  __shared__ float lcnt[POOL ? NG : 4];
  for (int i = threadIdx.x; i < DIM * DIM / 8; i += 256) {
    const float4* p = (const float4*)(W + (size_t)i * 8);
    float4 a = p[0], bq = p[1];
    uint4 o;
    o.x = bf16rne(a.x) | (bf16rne(a.y) << 16);
    o.y = bf16rne(a.z) | (bf16rne(a.w) << 16);
    o.z = bf16rne(bq.x) | (bf16rne(bq.y) << 16);
    o.w = bf16rne(bq.z) | (bf16rne(bq.w) << 16);
    ((uint4*)Wtb)[i] = o;
  }
  if (POOL) {
    for (int i = threadIdx.x; i < NG * DIM; i += 256) lsum[i] = 0.0f;
    if (threadIdx.x < NG) lcnt[threadIdx.x] = 0.0f;
  }
  __syncthreads();

  const int lane = threadIdx.x & 63;
  const int wid = threadIdx.x >> 6;
  const int g = lane >> 3;   // group 0..7 = which node
  const int idx = lane & 7;  // lane in group
  const int t8 = idx << 3;   // 8 dims per lane
  const float4 bb0 = *(const float4*)(b + t8);
  const float4 bb1 = *(const float4*)(b + t8 + 4);
  const int waveId = blockIdx.x * 4 + wid;
  const int stride8 = gridDim.x * 32;

  for (int n8 = waveId * 8; n8 < N; n8 += stride8) {
    int n = n8 + g;
    bool valid = n < N;
    int nc = valid ? n : 0;
    int base = rp2[nc];
    int end = rp2[nc + 1];
    float4 acc0 = make_float4(0.f, 0.f, 0.f, 0.f);
    float4 acc1 = make_float4(0.f, 0.f, 0.f, 0.f);
    for (int p = base; p < end; p += 8) {
      int4 c0 = *(const int4*)(col + p);
      int4 c1 = *(const int4*)(col + p + 4);
      uint4 u0 = *(const uint4*)(xb + ((size_t)c0.x << 6) + t8);
      uint4 u1 = *(const uint4*)(xb + ((size_t)c0.y << 6) + t8);
      uint4 u2 = *(const uint4*)(xb + ((size_t)c0.z << 6) + t8);
      uint4 u3 = *(const uint4*)(xb + ((size_t)c0.w << 6) + t8);
      uint4 u4 = *(const uint4*)(xb + ((size_t)c1.x << 6) + t8);
      uint4 u5 = *(const uint4*)(xb + ((size_t)c1.y << 6) + t8);
      uint4 u6 = *(const uint4*)(xb + ((size_t)c1.z << 6) + t8);
      uint4 u7 = *(const uint4*)(xb + ((size_t)c1.w << 6) + t8);
      acc0.x += (bflo(u0.x) + bflo(u1.x)) + (bflo(u2.x) + bflo(u3.x)) +
                (bflo(u4.x) + bflo(u5.x)) + (bflo(u6.x) + bflo(u7.x));
      acc0.y += (bfhi(u0.x) + bfhi(u1.x)) + (bfhi(u2.x) + bfhi(u3.x)) +
                (bfhi(u4.x) + bfhi(u5.x)) + (bfhi(u6.x) + bfhi(u7.x));
      acc0.z += (bflo(u0.y) + bflo(u1.y)) + (bflo(u2.y) + bflo(u3.y)) +
                (bflo(u4.y) + bflo(u5.y)) + (bflo(u6.y) + bflo(u7.y));
      acc0.w += (bfhi(u0.y) + bfhi(u1.y)) + (bfhi(u2.y) + bfhi(u3.y)) +
                (bfhi(u4.y) + bfhi(u5.y)) + (bfhi(u6.y) + bfhi(u7.y));
      acc1.x += (bflo(u0.z) + bflo(u1.z)) + (bflo(u2.z) + bflo(u3.z)) +
                (bflo(u4.z) + bflo(u5.z)) + (bflo(u6.z) + bflo(u7.z));
      acc1.y += (bfhi(u0.z) + bfhi(u1.z)) + (bfhi(u2.z) + bfhi(u3.z)) +
                (bfhi(u4.z) + bfhi(u5.z)) + (bfhi(u6.z) + bfhi(u7.z));
      acc1.z += (bflo(u0.w) + bflo(u1.w)) + (bflo(u2.w) + bflo(u3.w)) +
                (bflo(u4.w) + bflo(u5.w)) + (bflo(u6.w) + bflo(u7.w));
      acc1.w += (bfhi(u0.w) + bfhi(u1.w)) + (bfhi(u2.w) + bfhi(u3.w)) +
                (bfhi(u4.w) + bfhi(u5.w)) + (bfhi(u6.w) + bfhi(u7.w));
    }
    float dn = dnormA[nc];
    acc0.x *= dn; acc0.y *= dn; acc0.z *= dn; acc0.w *= dn;
    acc1.x *= dn; acc1.y *= dn; acc1.z *= dn; acc1.w *= dn;

    *(float4*)&aL[wid][g][t8] = acc0;
    *(float4*)&aL[wid][g][t8 + 4] = acc1;

    // MLP: lane owns out dims t8..t8+7; W in bf16 LDS
    float4 r0 = bb0, r1 = bb1;
#pragma unroll
    for (int kc = 0; kc < 16; ++kc) {
      float4 av = *(const float4*)&aL[wid][g][4 * kc];
#define FMA_K(s, avs)                                                         \
      {                                                                       \
        uint4 w = *(const uint4*)(Wtb + (4 * kc + s) * DIM + t8);             \
        r0.x = fmaf(avs, bflo(w.x), r0.x); r0.y = fmaf(avs, bfhi(w.x), r0.y); \
        r0.z = fmaf(avs, bflo(w.y), r0.z); r0.w = fmaf(avs, bfhi(w.y), r0.w); \
        r1.x = fmaf(avs, bflo(w.z), r1.x); r1.y = fmaf(avs, bfhi(w.z), r1.y); \
        r1.z = fmaf(avs, bflo(w.w), r1.z); r1.w = fmaf(avs, bfhi(w.w), r1.w); \
      }
      FMA_K(0, av.x) FMA_K(1, av.y) FMA_K(2, av.z) FMA_K(3, av.w)
#undef FMA_K
    }
    r0.x = fmaxf(r0.x, 0.f); r0.y = fmaxf(r0.y, 0.f);
    r0.z = fmaxf(r0.z, 0.f); r0.w = fmaxf(r0.w, 0.f);
    r1.x = fmaxf(r1.x, 0.f); r1.y = fmaxf(r1.y, 0.f);
    r1.z = fmaxf(r1.z, 0.f); r1.w = fmaxf(r1.w, 0.f);

    if (POOL) {
      if (valid) {
        int gi = gid[n];
        atomicAdd(&lsum[gi * DIM + t8 + 0], r0.x);
        atomicAdd(&lsum[gi * DIM + t8 + 1], r0.y);
        atomicAdd(&lsum[gi * DIM + t8 + 2], r0.z);
        atomicAdd(&lsum[gi * DIM + t8 + 3], r0.w);
        atomicAdd(&lsum[gi * DIM + t8 + 4], r1.x);
        atomicAdd(&lsum[gi * DIM + t8 + 5], r1.y);
        atomicAdd(&lsum[gi * DIM + t8 + 6], r1.z);
        atomicAdd(&lsum[gi * DIM + t8 + 7], r1.w);
        if (idx == 0) atomicAdd(&lcnt[gi], 1.0f);
      }
    } else if (valid) {
      float sn = snormA[n];
      uint4 o;
      o.x = bf16rne(r0.x * sn) | (bf16rne(r0.y * sn) << 16);
      o.y = bf16rne(r0.z * sn) | (bf16rne(r0.w * sn) << 16);
      o.z = bf16rne(r1.x * sn) | (bf16rne(r1.y * sn) << 16);
      o.w = bf16rne(r1.z * sn) | (bf16rne(r1.w * sn) << 16);
      *(uint4*)(outb + ((size_t)n << 6) + t8) = o;
    }
  }

  if (POOL) {
    __syncthreads();
    for (int i = threadIdx.x; i < NG * DIM; i += 256) atomicAdd(&gsum[i], lsum[i]);
    if (threadIdx.x < NG) atomicAdd(&gcnt[threadIdx.x], lcnt[threadIdx.x]);
  }
}

// ---- head ----
__global__ void final_kernel(const float* __restrict__ gsum, const float* __restrict__ gcnt,
                             const float* __restrict__ Wp, const float* __restrict__ bp,
                             float* __restrict__ out) {
  int lane = threadIdx.x;  // 64
#pragma unroll
  for (int g = 0; g < NG; ++g) {
    float inv = 1.0f / fmaxf(gcnt[g], 1.0f);
    float hv = gsum[g * DIM + lane] * inv;
#pragma unroll
    for (int c = 0; c < 2; ++c) {
      float p = hv * Wp[lane * 2 + c];
      for (int off = 32; off; off >>= 1) p += __shfl_down(p, off, 64);
      if (lane == 0) out[g * 2 + c] = p + bp[c];
    }
  }
}

extern "C" void kernel_launch(void* const* d_in, const int* in_sizes, int n_in,
                              void* d_out, int out_size, void* d_ws, size_t ws_size,
                              hipStream_t stream) {
  const float* features = (const float*)d_in[0];
  const float* W1 = (const float*)d_in[1];
  const float* b1 = (const float*)d_in[2];
  const float* W2 = (const float*)d_in[3];
  const float* b2 = (const float*)d_in[4];
  const float* Wp = (const float*)d_in[5];
  const float* bp = (const float*)d_in[6];
  const int* esrc = (const int*)d_in[7];
  const int* edst = (const int*)d_in[8];
  const int* gid = (const int*)d_in[9];
  float* out = (float*)d_out;

  const int N = NN;
  const size_t NPART = (size_t)2 * NR * GSL * RANGE;  // 6,422,528 ints

  float* base = (float*)d_ws;
  size_t off = 0;
  auto alloc = [&](size_t nwords) { size_t r = off; off = (off + nwords + 15) & ~(size_t)15; return r; };

  float* gsum = base + alloc(NG * DIM);   // zeroed
  float* gcnt = base + alloc(NG);         // zeroed
  size_t zeroWords = off;
  float* snormA = base + alloc(N);
  float* dnormA = base + alloc(N);
  int* rp2   = (int*)(base + alloc(N + 1));
  int* bsum  = (int*)(base + alloc(512));
  int* boff  = (int*)(base + alloc(512));
  int* col   = (int*)(base + alloc(COLCAP));
  int* partial = (int*)(base + alloc(NPART));
  unsigned short* xb = (unsigned short*)(base + alloc((size_t)(N + 1) * DIM / 2));
  unsigned short* Bb = (unsigned short*)(base + alloc((size_t)(N + 1) * DIM / 2));

  hipMemsetAsync(d_ws, 0, zeroWords * sizeof(float), stream);
  hipMemsetAsync(xb + (size_t)N * DIM, 0, DIM * sizeof(unsigned short), stream);
  hipMemsetAsync(Bb + (size_t)N * DIM, 0, DIM * sizeof(unsigned short), stream);

  hist_kernel<<<2 * NR * GSL, 256, 0, stream>>>((const int4*)esrc, (const int4*)edst, partial);

  scan1_kernel<<<NB, SCAN_BS, 0, stream>>>(partial, snormA, dnormA, rp2, bsum, N);
  scan2_kernel<<<1, 512, 0, stream>>>(bsum, boff, NB);
  scan3_kernel<<<NB, SCAN_BS, 0, stream>>>(rp2, boff, N);

  offscan_kernel<<<(NR * RANGE + 255) / 256, 256, 0, stream>>>(partial, rp2, N);
  colinit_kernel<<<(COLCAP / 4 + 255) / 256, 256, 0, stream>>>((int4*)col, COLCAP / 4);
  fill_kernel<<<NR * GSL, 256, 0, stream>>>((const int4*)esrc, (const int4*)edst, partial, col);

  prescale_kernel<<<(N * 8 + 255) / 256, 256, 0, stream>>>(features, snormA, xb, N);

  // layer 1: xb -> Bb = bf16(relu(gather(xb)*dnorm @ W1 + b1) * snorm)
  gconv_kernel<0><<<2048, 256, 0, stream>>>(xb, snormA, dnormA, rp2, col, W1, b1,
                                            Bb, gid, gsum, gcnt, N);
  // layer 2: Bb -> pooled gsum/gcnt
  gconv_kernel<1><<<2048, 256, 0, stream>>>(Bb, snormA, dnormA, rp2, col, W2, b2,
                                            nullptr, gid, gsum, gcnt, N);

  final_kernel<<<1, 64, 0, stream>>>(gsum, gcnt, Wp, bp, out);
}

// Round 24
// 209.264 us; speedup vs baseline: 1.8095x; 1.8095x over previous
//
#include <hip/hip_runtime.h>

#define NN 100000
#define NE 1200000
#define NG 8
#define DIM 64
#define SCAN_BS 256
#define NB ((NN + SCAN_BS - 1) / SCAN_BS)  // 391
#define COLCAP (NE + 7 * NN)  // ceil8 padding worst case

// histogram partition: 7 ranges x 16384 nodes (64KB LDS), 28 edge slices
#define RANGE 16384
#define RSH 14
#define NR 7
#define GSL 28
#define SLICE4 ((NE / 4 + GSL - 1) / GSL)  // 10715

__device__ __forceinline__ unsigned bf16rne(float f) {
  unsigned u = __float_as_uint(f);
  return (u + 0x7FFF + ((u >> 16) & 1)) >> 16;
}
__device__ __forceinline__ float bflo(unsigned u) { return __uint_as_float(u << 16); }
__device__ __forceinline__ float bfhi(unsigned u) { return __uint_as_float(u & 0xFFFF0000u); }

// ---- range-partitioned LDS histogram ----
__global__ __launch_bounds__(256) void hist_kernel(const int4* __restrict__ esrc4,
                                                   const int4* __restrict__ edst4,
                                                   int* __restrict__ partial) {
  __shared__ int h[RANGE];
  int job = blockIdx.x;
  int g = job % GSL;
  int r = (job / GSL) % NR;
  int dir = job / (GSL * NR);
  const int4* __restrict__ idx = dir ? edst4 : esrc4;
  int lo = r * RANGE, hi = min(lo + RANGE, NN);
  for (int i = threadIdx.x; i < RANGE / 4; i += 256) ((int4*)h)[i] = make_int4(0, 0, 0, 0);
  __syncthreads();
  int s0 = g * SLICE4, s1 = min(s0 + SLICE4, NE / 4);
  for (int i = s0 + threadIdx.x; i < s1; i += 256) {
    int4 v = idx[i];
    if (v.x >= lo && v.x < hi) atomicAdd(&h[v.x - lo], 1);
    if (v.y >= lo && v.y < hi) atomicAdd(&h[v.y - lo], 1);
    if (v.z >= lo && v.z < hi) atomicAdd(&h[v.z - lo], 1);
    if (v.w >= lo && v.w < hi) atomicAdd(&h[v.w - lo], 1);
  }
  __syncthreads();
  int4* dst = (int4*)(partial + (size_t)job * RANGE);
  int cap4 = (hi - lo) >> 2;
  for (int i = threadIdx.x; i < cap4; i += 256) dst[i] = ((int4*)h)[i];
}

// ---- fused reduce + scan1 ----
__global__ __launch_bounds__(SCAN_BS) void scan1_kernel(const int* __restrict__ partial,
                                                        float* __restrict__ snormA,
                                                        float* __restrict__ dnormA,
                                                        int* __restrict__ rp2,
                                                        int* __restrict__ bsum, int N) {
  __shared__ int t[SCAN_BS];
  int i = blockIdx.x * SCAN_BS + threadIdx.x;
  int v = 0;
  if (i < N) {
    int r = i >> RSH, off = i & (RANGE - 1);
    const int* ps = partial + ((size_t)r * GSL) * RANGE + off;
    const int* pd = partial + (((size_t)NR + r) * GSL) * RANGE + off;
    int sOut = 0, sIn = 0;
#pragma unroll
    for (int g = 0; g < GSL; ++g) {
      sOut += ps[(size_t)g * RANGE];
      sIn += pd[(size_t)g * RANGE];
    }
    snormA[i] = rsqrtf(fmaxf((float)sOut, 1.0f));
    dnormA[i] = rsqrtf(fmaxf((float)sIn, 1.0f));
    v = (sIn + 7) & ~7;
  }
  t[threadIdx.x] = v;
  __syncthreads();
  for (int off = 1; off < SCAN_BS; off <<= 1) {
    int u = (threadIdx.x >= off) ? t[threadIdx.x - off] : 0;
    __syncthreads();
    t[threadIdx.x] += u;
    __syncthreads();
  }
  if (i < N) rp2[i] = t[threadIdx.x] - v;
  if (i == N - 1) rp2[N] = t[threadIdx.x];
  if (threadIdx.x == SCAN_BS - 1) bsum[blockIdx.x] = t[threadIdx.x];
}

__global__ __launch_bounds__(512) void scan2_kernel(const int* __restrict__ bsum,
                                                    int* __restrict__ boff, int nb) {
  __shared__ int t[512];
  int v = ((int)threadIdx.x < nb) ? bsum[threadIdx.x] : 0;
  t[threadIdx.x] = v;
  __syncthreads();
  for (int off = 1; off < 512; off <<= 1) {
    int u = (threadIdx.x >= off) ? t[threadIdx.x - off] : 0;
    __syncthreads();
    t[threadIdx.x] += u;
    __syncthreads();
  }
  boff[threadIdx.x] = t[threadIdx.x] - v;
}

__global__ __launch_bounds__(SCAN_BS) void scan3_kernel(int* __restrict__ rp2,
                                                        const int* __restrict__ boff, int N) {
  int i = blockIdx.x * SCAN_BS + threadIdx.x;
  if (i < N) rp2[i] += boff[blockIdx.x];
  if (i == N - 1) rp2[N] += boff[blockIdx.x];
}

// ---- in-place: partial[1][r][g][i] -> absolute start offset ----
__global__ void offscan_kernel(int* __restrict__ partial, const int* __restrict__ rp2, int N) {
  int n = blockIdx.x * blockDim.x + threadIdx.x;
  if (n >= N) return;
  int r = n >> RSH, i = n & (RANGE - 1);
  int* p = partial + (((size_t)NR + r) * GSL) * RANGE + i;
  int running = rp2[n];
#pragma unroll
  for (int g = 0; g < GSL; ++g) {
    int tmp = p[(size_t)g * RANGE];
    p[(size_t)g * RANGE] = running;
    running += tmp;
  }
}

// ---- init col with NN (zero-row index) ----
__global__ void colinit_kernel(int4* __restrict__ col4, int n4) {
  int i = blockIdx.x * blockDim.x + threadIdx.x;
  int st = gridDim.x * blockDim.x;
  for (; i < n4; i += st) col4[i] = make_int4(NN, NN, NN, NN);
}

// ---- fill CSR col ----
__global__ __launch_bounds__(256) void fill_kernel(const int4* __restrict__ esrc4,
                                                   const int4* __restrict__ edst4,
                                                   const int* __restrict__ partial,
                                                   int* __restrict__ col) {
  __shared__ int cnt[RANGE];
  int job = blockIdx.x;  // NR*GSL
  int g = job % GSL, r = job / GSL;
  int lo = r * RANGE, hi = min(lo + RANGE, NN);
  const int* off = partial + (((size_t)NR + r) * GSL + g) * RANGE;
  for (int i = threadIdx.x; i < hi - lo; i += 256) cnt[i] = off[i];
  __syncthreads();
  int s0 = g * SLICE4, s1 = min(s0 + SLICE4, NE / 4);
  for (int i = s0 + threadIdx.x; i < s1; i += 256) {
    int4 d = edst4[i];
    int4 s = esrc4[i];
    if (d.x >= lo && d.x < hi) col[atomicAdd(&cnt[d.x - lo], 1)] = s.x;
    if (d.y >= lo && d.y < hi) col[atomicAdd(&cnt[d.y - lo], 1)] = s.y;
    if (d.z >= lo && d.z < hi) col[atomicAdd(&cnt[d.z - lo], 1)] = s.z;
    if (d.w >= lo && d.w < hi) col[atomicAdd(&cnt[d.w - lo], 1)] = s.w;
  }
}

// ---- xb = bf16(features * snorm), RNE ----
__global__ void prescale_kernel(const float* __restrict__ f, const float* __restrict__ snormA,
                                unsigned short* __restrict__ xb, int N) {
  int i = blockIdx.x * blockDim.x + threadIdx.x;  // 8-elem chunk
  if (i < N * 8) {
    int n = i >> 3;
    float sn = snormA[n];
    const float4* p = (const float4*)(f + (size_t)i * 8);
    float4 a = p[0], b = p[1];
    uint4 o;
    o.x = bf16rne(a.x * sn) | (bf16rne(a.y * sn) << 16);
    o.y = bf16rne(a.z * sn) | (bf16rne(a.w * sn) << 16);
    o.z = bf16rne(b.x * sn) | (bf16rne(b.y * sn) << 16);
    o.w = bf16rne(b.z * sn) | (bf16rne(b.w * sn) << 16);
    ((uint4*)xb)[i] = o;
  }
}

// ---- fused gather(bf16) + dnorm + MLP(relu); 8 nodes/wave; 512-thread blocks ----
// R21 gconv body (fp32 Wt, VGPR~48); 8 waves share one Wt -> 4 blocks/CU = 32 waves/CU.
template <int POOL>
__global__ __launch_bounds__(512) void gconv_kernel(
    const unsigned short* __restrict__ xb, const float* __restrict__ snormA,
    const float* __restrict__ dnormA,
    const int* __restrict__ rp2, const int* __restrict__ col,
    const float* __restrict__ W, const float* __restrict__ b,
    unsigned short* __restrict__ outb, const int* __restrict__ gid,
    float* __restrict__ gsum, float* __restrict__ gcnt, int N) {
  __shared__ float Wt[DIM * DIM];      // fp32 W, 16KB (shared by 8 waves)
  __shared__ float aL[8][8][DIM + 1];  // [wave][group][dim] padded
  __shared__ float lsum[NG * DIM];
  __shared__ float lcnt[NG];
  for (int i = threadIdx.x; i < DIM * 16; i += 512) {
    int k = i >> 4, ch = i & 15;
    *(float4*)&Wt[k * DIM + ch * 4] = *(const float4*)(W + k * DIM + ch * 4);
  }
  if (POOL) {
    for (int i = threadIdx.x; i < NG * DIM; i += 512) lsum[i] = 0.0f;
    if (threadIdx.x < NG) lcnt[threadIdx.x] = 0.0f;
  }
  __syncthreads();

  const int lane = threadIdx.x & 63;
  const int wid = threadIdx.x >> 6;  // 0..7
  const int g = lane >> 3;   // group 0..7 = which node
  const int idx = lane & 7;  // lane in group
  const int t8 = idx << 3;   // 8 dims per lane
  const float4 bb0 = *(const float4*)(b + t8);
  const float4 bb1 = *(const float4*)(b + t8 + 4);
  const int waveId = blockIdx.x * 8 + wid;
  const int stride8 = gridDim.x * 64;

  for (int n8 = waveId * 8; n8 < N; n8 += stride8) {
    int n = n8 + g;
    bool valid = n < N;
    int nc = valid ? n : 0;
    int base = rp2[nc];
    int end = rp2[nc + 1];
    float4 acc0 = make_float4(0.f, 0.f, 0.f, 0.f);
    float4 acc1 = make_float4(0.f, 0.f, 0.f, 0.f);
    for (int p = base; p < end; p += 8) {
      int4 c0 = *(const int4*)(col + p);
      int4 c1 = *(const int4*)(col + p + 4);
      uint4 u0 = *(const uint4*)(xb + ((size_t)c0.x << 6) + t8);
      uint4 u1 = *(const uint4*)(xb + ((size_t)c0.y << 6) + t8);
      uint4 u2 = *(const uint4*)(xb + ((size_t)c0.z << 6) + t8);
      uint4 u3 = *(const uint4*)(xb + ((size_t)c0.w << 6) + t8);
      uint4 u4 = *(const uint4*)(xb + ((size_t)c1.x << 6) + t8);
      uint4 u5 = *(const uint4*)(xb + ((size_t)c1.y << 6) + t8);
      uint4 u6 = *(const uint4*)(xb + ((size_t)c1.z << 6) + t8);
      uint4 u7 = *(const uint4*)(xb + ((size_t)c1.w << 6) + t8);
      acc0.x += (bflo(u0.x) + bflo(u1.x)) + (bflo(u2.x) + bflo(u3.x)) +
                (bflo(u4.x) + bflo(u5.x)) + (bflo(u6.x) + bflo(u7.x));
      acc0.y += (bfhi(u0.x) + bfhi(u1.x)) + (bfhi(u2.x) + bfhi(u3.x)) +
                (bfhi(u4.x) + bfhi(u5.x)) + (bfhi(u6.x) + bfhi(u7.x));
      acc0.z += (bflo(u0.y) + bflo(u1.y)) + (bflo(u2.y) + bflo(u3.y)) +
                (bflo(u4.y) + bflo(u5.y)) + (bflo(u6.y) + bflo(u7.y));
      acc0.w += (bfhi(u0.y) + bfhi(u1.y)) + (bfhi(u2.y) + bfhi(u3.y)) +
                (bfhi(u4.y) + bfhi(u5.y)) + (bfhi(u6.y) + bfhi(u7.y));
      acc1.x += (bflo(u0.z) + bflo(u1.z)) + (bflo(u2.z) + bflo(u3.z)) +
                (bflo(u4.z) + bflo(u5.z)) + (bflo(u6.z) + bflo(u7.z));
      acc1.y += (bfhi(u0.z) + bfhi(u1.z)) + (bfhi(u2.z) + bfhi(u3.z)) +
                (bfhi(u4.z) + bfhi(u5.z)) + (bfhi(u6.z) + bfhi(u7.z));
      acc1.z += (bflo(u0.w) + bflo(u1.w)) + (bflo(u2.w) + bflo(u3.w)) +
                (bflo(u4.w) + bflo(u5.w)) + (bflo(u6.w) + bflo(u7.w));
      acc1.w += (bfhi(u0.w) + bfhi(u1.w)) + (bfhi(u2.w) + bfhi(u3.w)) +
                (bfhi(u4.w) + bfhi(u5.w)) + (bfhi(u6.w) + bfhi(u7.w));
    }
    float dn = dnormA[nc];
    acc0.x *= dn; acc0.y *= dn; acc0.z *= dn; acc0.w *= dn;
    acc1.x *= dn; acc1.y *= dn; acc1.z *= dn; acc1.w *= dn;

    *(float4*)&aL[wid][g][t8] = acc0;
    *(float4*)&aL[wid][g][t8 + 4] = acc1;

    // MLP: lane owns out dims t8..t8+7; fp32 W in LDS (R21 codegen)
    float4 r0 = bb0, r1 = bb1;
#pragma unroll
    for (int kc = 0; kc < 16; ++kc) {
      float4 av = *(const float4*)&aL[wid][g][4 * kc];
#define FMA_K(s, avs)                                                     \
      {                                                                   \
        const float* wr = Wt + (4 * kc + s) * DIM;                        \
        float4 wA = *(const float4*)(wr + t8);                            \
        float4 wB = *(const float4*)(wr + t8 + 4);                        \
        r0.x = fmaf(avs, wA.x, r0.x); r0.y = fmaf(avs, wA.y, r0.y);       \
        r0.z = fmaf(avs, wA.z, r0.z); r0.w = fmaf(avs, wA.w, r0.w);       \
        r1.x = fmaf(avs, wB.x, r1.x); r1.y = fmaf(avs, wB.y, r1.y);       \
        r1.z = fmaf(avs, wB.z, r1.z); r1.w = fmaf(avs, wB.w, r1.w);       \
      }
      FMA_K(0, av.x) FMA_K(1, av.y) FMA_K(2, av.z) FMA_K(3, av.w)
#undef FMA_K
    }
    r0.x = fmaxf(r0.x, 0.f); r0.y = fmaxf(r0.y, 0.f);
    r0.z = fmaxf(r0.z, 0.f); r0.w = fmaxf(r0.w, 0.f);
    r1.x = fmaxf(r1.x, 0.f); r1.y = fmaxf(r1.y, 0.f);
    r1.z = fmaxf(r1.z, 0.f); r1.w = fmaxf(r1.w, 0.f);

    if (POOL) {
      if (valid) {
        int gi = gid[n];
        atomicAdd(&lsum[gi * DIM + t8 + 0], r0.x);
        atomicAdd(&lsum[gi * DIM + t8 + 1], r0.y);
        atomicAdd(&lsum[gi * DIM + t8 + 2], r0.z);
        atomicAdd(&lsum[gi * DIM + t8 + 3], r0.w);
        atomicAdd(&lsum[gi * DIM + t8 + 4], r1.x);
        atomicAdd(&lsum[gi * DIM + t8 + 5], r1.y);
        atomicAdd(&lsum[gi * DIM + t8 + 6], r1.z);
        atomicAdd(&lsum[gi * DIM + t8 + 7], r1.w);
        if (idx == 0) atomicAdd(&lcnt[gi], 1.0f);
      }
    } else if (valid) {
      float sn = snormA[n];
      uint4 o;
      o.x = bf16rne(r0.x * sn) | (bf16rne(r0.y * sn) << 16);
      o.y = bf16rne(r0.z * sn) | (bf16rne(r0.w * sn) << 16);
      o.z = bf16rne(r1.x * sn) | (bf16rne(r1.y * sn) << 16);
      o.w = bf16rne(r1.z * sn) | (bf16rne(r1.w * sn) << 16);
      *(uint4*)(outb + ((size_t)n << 6) + t8) = o;
    }
  }

  if (POOL) {
    __syncthreads();
    for (int i = threadIdx.x; i < NG * DIM; i += 512) atomicAdd(&gsum[i], lsum[i]);
    if (threadIdx.x < NG) atomicAdd(&gcnt[threadIdx.x], lcnt[threadIdx.x]);
  }
}

// ---- head ----
__global__ void final_kernel(const float* __restrict__ gsum, const float* __restrict__ gcnt,
                             const float* __restrict__ Wp, const float* __restrict__ bp,
                             float* __restrict__ out) {
  int lane = threadIdx.x;  // 64
#pragma unroll
  for (int g = 0; g < NG; ++g) {
    float inv = 1.0f / fmaxf(gcnt[g], 1.0f);
    float hv = gsum[g * DIM + lane] * inv;
#pragma unroll
    for (int c = 0; c < 2; ++c) {
      float p = hv * Wp[lane * 2 + c];
      for (int off = 32; off; off >>= 1) p += __shfl_down(p, off, 64);
      if (lane == 0) out[g * 2 + c] = p + bp[c];
    }
  }
}

extern "C" void kernel_launch(void* const* d_in, const int* in_sizes, int n_in,
                              void* d_out, int out_size, void* d_ws, size_t ws_size,
                              hipStream_t stream) {
  const float* features = (const float*)d_in[0];
  const float* W1 = (const float*)d_in[1];
  const float* b1 = (const float*)d_in[2];
  const float* W2 = (const float*)d_in[3];
  const float* b2 = (const float*)d_in[4];
  const float* Wp = (const float*)d_in[5];
  const float* bp = (const float*)d_in[6];
  const int* esrc = (const int*)d_in[7];
  const int* edst = (const int*)d_in[8];
  const int* gid = (const int*)d_in[9];
  float* out = (float*)d_out;

  const int N = NN;
  const size_t NPART = (size_t)2 * NR * GSL * RANGE;  // 6,422,528 ints

  float* base = (float*)d_ws;
  size_t off = 0;
  auto alloc = [&](size_t nwords) { size_t r = off; off = (off + nwords + 15) & ~(size_t)15; return r; };

  float* gsum = base + alloc(NG * DIM);   // zeroed
  float* gcnt = base + alloc(NG);         // zeroed
  size_t zeroWords = off;
  float* snormA = base + alloc(N);
  float* dnormA = base + alloc(N);
  int* rp2   = (int*)(base + alloc(N + 1));
  int* bsum  = (int*)(base + alloc(512));
  int* boff  = (int*)(base + alloc(512));
  int* col   = (int*)(base + alloc(COLCAP));
  int* partial = (int*)(base + alloc(NPART));
  unsigned short* xb = (unsigned short*)(base + alloc((size_t)(N + 1) * DIM / 2));
  unsigned short* Bb = (unsigned short*)(base + alloc((size_t)(N + 1) * DIM / 2));

  hipMemsetAsync(d_ws, 0, zeroWords * sizeof(float), stream);
  hipMemsetAsync(xb + (size_t)N * DIM, 0, DIM * sizeof(unsigned short), stream);
  hipMemsetAsync(Bb + (size_t)N * DIM, 0, DIM * sizeof(unsigned short), stream);

  hist_kernel<<<2 * NR * GSL, 256, 0, stream>>>((const int4*)esrc, (const int4*)edst, partial);

  scan1_kernel<<<NB, SCAN_BS, 0, stream>>>(partial, snormA, dnormA, rp2, bsum, N);
  scan2_kernel<<<1, 512, 0, stream>>>(bsum, boff, NB);
  scan3_kernel<<<NB, SCAN_BS, 0, stream>>>(rp2, boff, N);

  offscan_kernel<<<(NR * RANGE + 255) / 256, 256, 0, stream>>>(partial, rp2, N);
  colinit_kernel<<<(COLCAP / 4 + 255) / 256, 256, 0, stream>>>((int4*)col, COLCAP / 4);
  fill_kernel<<<NR * GSL, 256, 0, stream>>>((const int4*)esrc, (const int4*)edst, partial, col);

  prescale_kernel<<<(N * 8 + 255) / 256, 256, 0, stream>>>(features, snormA, xb, N);

  // layer 1: xb -> Bb = bf16(relu(gather(xb)*dnorm @ W1 + b1) * snorm)
  gconv_kernel<0><<<1024, 512, 0, stream>>>(xb, snormA, dnormA, rp2, col, W1, b1,
                                            Bb, gid, gsum, gcnt, N);
  // layer 2: Bb -> pooled gsum/gcnt
  gconv_kernel<1><<<1024, 512, 0, stream>>>(Bb, snormA, dnormA, rp2, col, W2, b2,
                                            nullptr, gid, gsum, gcnt, N);

  final_kernel<<<1, 64, 0, stream>>>(gsum, gcnt, Wp, bp, out);
}